// Round 3
// baseline (1054.691 us; speedup 1.0000x reference)
//
#include <hip/hip_runtime.h>
#include <hip/hip_bf16.h>
#include <math.h>

// ---------------------------------------------------------------------------
// DLRM forward: bottom MLP -> embedding gather + pairwise interaction -> top MLP
// B=16384, D=64, 26 tables, all f32 (CDNA4 has no fp32 MFMA -> vector ALU).
// ---------------------------------------------------------------------------

#define BATCH 16384
#define NTAB 26
#define NF 27          // 1 + NTAB rows in interaction
#define NROWS 100000
#define EDIM 64
#define PAIRS 351      // 27*26/2
#define RLD 416        // padded leading dim of R (415 -> 416, 16B aligned)

// ---------------------------------------------------------------------------
// f32 GEMM:  C[M,N] = act(A[M,K] @ W[N,K]^T + bias)
// A row-major (lda), W row-major (ldw): both K-contiguous.
// 256 threads. VEC=true requires K%BK==0, lda%4==0, ldw%4==0 (no guards,
// float4 global + LDS). LDS rows padded +4: keeps 16B alignment and breaks
// power-of-2 stride (2-way bank aliasing is free on gfx950, m136).
// ---------------------------------------------------------------------------
template<int BM, int BN, int BK, int TM, int TN, bool VEC, bool RELU>
__global__ __launch_bounds__(256) void gemm_bias_act(
    const float* __restrict__ A, int lda,
    const float* __restrict__ W, int ldw,
    const float* __restrict__ bias,
    float* __restrict__ C, int ldc,
    int M, int N, int K)
{
    __shared__ float As[BK][BM + 4];
    __shared__ float Ws[BK][BN + 4];

    const int tid  = threadIdx.x;
    const int mblk = blockIdx.x * BM;
    const int nblk = blockIdx.y * BN;

    const int tcol = tid % (BN / TN);
    const int trow = tid / (BN / TN);
    const int m0 = trow * TM;
    const int n0 = tcol * TN;

    float acc[TM][TN];
#pragma unroll
    for (int i = 0; i < TM; ++i)
#pragma unroll
        for (int j = 0; j < TN; ++j) acc[i][j] = 0.f;

    const int ktiles = (K + BK - 1) / BK;
    for (int kt = 0; kt < ktiles; ++kt) {
        const int k0 = kt * BK;
        if (VEC) {
            // A tile: BM*BK/4 float4 loads across 256 threads
#pragma unroll
            for (int i = 0; i < (BM * BK) / (4 * 256); ++i) {
                int idx = tid + i * 256;
                int am = idx / (BK / 4);
                int a4 = idx % (BK / 4);
                float4 v = *(const float4*)&A[(size_t)(mblk + am) * lda + k0 + a4 * 4];
                As[a4 * 4 + 0][am] = v.x;
                As[a4 * 4 + 1][am] = v.y;
                As[a4 * 4 + 2][am] = v.z;
                As[a4 * 4 + 3][am] = v.w;
            }
#pragma unroll
            for (int i = 0; i < (BN * BK) / (4 * 256); ++i) {
                int idx = tid + i * 256;
                int wn = idx / (BK / 4);
                int w4 = idx % (BK / 4);
                float4 v = *(const float4*)&W[(size_t)(nblk + wn) * ldw + k0 + w4 * 4];
                Ws[w4 * 4 + 0][wn] = v.x;
                Ws[w4 * 4 + 1][wn] = v.y;
                Ws[w4 * 4 + 2][wn] = v.z;
                Ws[w4 * 4 + 3][wn] = v.w;
            }
        } else {
#pragma unroll
            for (int i = 0; i < (BM * BK) / 256; ++i) {
                int idx = tid + i * 256;
                int am = idx / BK;
                int ak = idx % BK;
                int gk = k0 + ak;
                float v = 0.f;
                if (gk < K) v = A[(size_t)(mblk + am) * lda + gk];
                As[ak][am] = v;
            }
#pragma unroll
            for (int i = 0; i < (BN * BK) / 256; ++i) {
                int idx = tid + i * 256;
                int wn = idx / BK;
                int wk = idx % BK;
                int gk = k0 + wk;
                float v = 0.f;
                if (gk < K) v = W[(size_t)(nblk + wn) * ldw + gk];
                Ws[wk][wn] = v;
            }
        }
        __syncthreads();

#pragma unroll
        for (int k = 0; k < BK; ++k) {
            float a[TM], b[TN];
            if (VEC) {
#pragma unroll
                for (int i = 0; i < TM; i += 4) {
                    float4 t = *(const float4*)&As[k][m0 + i];
                    a[i] = t.x; a[i + 1] = t.y; a[i + 2] = t.z; a[i + 3] = t.w;
                }
#pragma unroll
                for (int j = 0; j < TN; j += 4) {
                    float4 t = *(const float4*)&Ws[k][n0 + j];
                    b[j] = t.x; b[j + 1] = t.y; b[j + 2] = t.z; b[j + 3] = t.w;
                }
            } else {
#pragma unroll
                for (int i = 0; i < TM; ++i) a[i] = As[k][m0 + i];
#pragma unroll
                for (int j = 0; j < TN; ++j) b[j] = Ws[k][n0 + j];
            }
#pragma unroll
            for (int i = 0; i < TM; ++i)
#pragma unroll
                for (int j = 0; j < TN; ++j)
                    acc[i][j] += a[i] * b[j];
        }
        __syncthreads();
    }

#pragma unroll
    for (int i = 0; i < TM; ++i) {
        int gm = mblk + m0 + i;
        if (VEC) {
#pragma unroll
            for (int j = 0; j < TN; j += 4) {
                int gn = nblk + n0 + j;
                float4 o;
                o.x = acc[i][j + 0] + bias[gn + 0];
                o.y = acc[i][j + 1] + bias[gn + 1];
                o.z = acc[i][j + 2] + bias[gn + 2];
                o.w = acc[i][j + 3] + bias[gn + 3];
                if (RELU) {
                    o.x = o.x > 0.f ? o.x : 0.f;
                    o.y = o.y > 0.f ? o.y : 0.f;
                    o.z = o.z > 0.f ? o.z : 0.f;
                    o.w = o.w > 0.f ? o.w : 0.f;
                }
                *(float4*)&C[(size_t)gm * ldc + gn] = o;
            }
        } else {
#pragma unroll
            for (int j = 0; j < TN; ++j) {
                int gn = nblk + n0 + j;
                float v = acc[i][j] + bias[gn];
                if (RELU) v = v > 0.f ? v : 0.f;
                C[(size_t)gm * ldc + gn] = v;
            }
        }
    }
}

// ---------------------------------------------------------------------------
// Pad top_w0 [512][415] -> Wpad [512][416] with col 415 = 0.
// ---------------------------------------------------------------------------
__global__ __launch_bounds__(256) void pad_w0_kernel(
    const float* __restrict__ w, float* __restrict__ wp)
{
    int idx = blockIdx.x * 256 + threadIdx.x;
    if (idx < 512 * 416) {
        int n = idx / 416, k = idx % 416;
        wp[idx] = (k < 415) ? w[n * 415 + k] : 0.f;
    }
}

// ---------------------------------------------------------------------------
// Fused embedding gather + pairwise interaction.
// One wave per batch row (4 rows / block). Stages the 27x64 T-matrix in LDS,
// then computes the 351 lower-triangle dots into R[b][64..414]; zeroes col 415.
// ---------------------------------------------------------------------------
__global__ __launch_bounds__(256) void interact_kernel(
    const float* __restrict__ emb,   // [26][100000][64]
    const int*   __restrict__ lsi,   // [26][B]
    float* __restrict__ R)           // [B][RLD]
{
    __shared__ float Tl[4][NF][68];  // row stride 68 floats (16B aligned)

    const int wave = threadIdx.x >> 6;
    const int lane = threadIdx.x & 63;
    const int b = blockIdx.x * 4 + wave;

    Tl[wave][0][lane] = R[(size_t)b * RLD + lane];   // row 0: x
#pragma unroll 2
    for (int t = 0; t < NTAB; ++t) {
        int row = lsi[t * BATCH + b];
        Tl[wave][t + 1][lane] = emb[((size_t)t * NROWS + row) * EDIM + lane];
    }
    __syncthreads();

    for (int p = lane; p < PAIRS; p += 64) {
        // decode p -> (i, j): tril order, p = i*(i-1)/2 + j, j < i
        int i = (int)((1.0f + sqrtf(1.0f + 8.0f * (float)p)) * 0.5f);
        while (i * (i - 1) / 2 > p) --i;
        while ((i + 1) * i / 2 <= p) ++i;
        int j = p - i * (i - 1) / 2;

        const float4* ri = (const float4*)&Tl[wave][i][0];
        const float4* rj = (const float4*)&Tl[wave][j][0];
        float s = 0.f;
#pragma unroll
        for (int d = 0; d < EDIM / 4; ++d) {
            float4 a = ri[d], c = rj[d];
            s += a.x * c.x + a.y * c.y + a.z * c.z + a.w * c.w;
        }
        R[(size_t)b * RLD + EDIM + p] = s;
    }
    if (lane == 0) R[(size_t)b * RLD + EDIM + PAIRS] = 0.f;  // col 415 = 0 (K=416 GEMM)
}

// ---------------------------------------------------------------------------
// Final layer: out[b] = sigmoid(dot(h[b], w) + bias). One wave per row.
// ---------------------------------------------------------------------------
__global__ __launch_bounds__(256) void top_final_kernel(
    const float* __restrict__ h,     // [B][256]
    const float* __restrict__ w,     // [256]
    const float* __restrict__ bias,  // [1]
    float* __restrict__ out)
{
    const int wave = threadIdx.x >> 6;
    const int lane = threadIdx.x & 63;
    const int b = blockIdx.x * 4 + wave;

    const float4* hv = (const float4*)&h[(size_t)b * 256];
    const float4* wv = (const float4*)w;
    float4 a = hv[lane];
    float4 c = wv[lane];
    float s = a.x * c.x + a.y * c.y + a.z * c.z + a.w * c.w;
#pragma unroll
    for (int off = 32; off; off >>= 1) s += __shfl_down(s, off);
    if (lane == 0) {
        float z = s + bias[0];
        out[b] = 1.f / (1.f + expf(-z));
    }
}

// ---------------------------------------------------------------------------
extern "C" void kernel_launch(void* const* d_in, const int* in_sizes, int n_in,
                              void* d_out, int out_size, void* d_ws, size_t ws_size,
                              hipStream_t stream)
{
    const float* dense_x = (const float*)d_in[0];
    const int*   lS_i    = (const int*)  d_in[1];
    const float* emb_W   = (const float*)d_in[2];
    const float* bot_w0  = (const float*)d_in[3];
    const float* bot_b0  = (const float*)d_in[4];
    const float* bot_w1  = (const float*)d_in[5];
    const float* bot_b1  = (const float*)d_in[6];
    const float* bot_w2  = (const float*)d_in[7];
    const float* bot_b2  = (const float*)d_in[8];
    const float* top_w0  = (const float*)d_in[9];
    const float* top_b0  = (const float*)d_in[10];
    const float* top_w1  = (const float*)d_in[11];
    const float* top_b1  = (const float*)d_in[12];
    const float* top_w2  = (const float*)d_in[13];
    const float* top_b2  = (const float*)d_in[14];
    float* out = (float*)d_out;

    // workspace layout (floats)
    float* R    = (float*)d_ws;                       // [B][416]   27.3 MB
    float* hA   = R    + (size_t)BATCH * RLD;         // [B][512]   33.6 MB
    float* hB   = hA   + (size_t)BATCH * 512;         // [B][256]   16.8 MB
    float* Wpad = hB   + (size_t)BATCH * 256;         // [512][416]  0.9 MB

    dim3 blk(256);

    // pad top_w0 (needed before top L0; issue first, it's tiny)
    pad_w0_kernel<<<dim3((512 * 416 + 255) / 256), blk, 0, stream>>>(top_w0, Wpad);

    // ---- bottom MLP ----
    // L0: [B,13] -> [B,512]   (K=13: guarded scalar path)
    gemm_bias_act<128, 64, 16, 8, 4, false, true><<<dim3(BATCH / 128, 512 / 64), blk, 0, stream>>>(
        dense_x, 13, bot_w0, 13, bot_b0, hA, 512, BATCH, 512, 13);
    // L1: [B,512] -> [B,256]
    gemm_bias_act<128, 128, 16, 8, 8, true, true><<<dim3(BATCH / 128, 256 / 128), blk, 0, stream>>>(
        hA, 512, bot_w1, 512, bot_b1, hB, 256, BATCH, 256, 512);
    // L2: [B,256] -> [B,64] written into R[:,0:64]
    gemm_bias_act<128, 64, 16, 8, 4, true, true><<<dim3(BATCH / 128, 64 / 64), blk, 0, stream>>>(
        hB, 256, bot_w2, 256, bot_b2, R, RLD, BATCH, 64, 256);

    // ---- gather + interaction -> R[:,64:415], R[:,415]=0 ----
    interact_kernel<<<dim3(BATCH / 4), blk, 0, stream>>>(emb_W, lS_i, R);

    // ---- top MLP ----
    // L0: [B,416pad] -> [B,512]
    gemm_bias_act<128, 128, 16, 8, 8, true, true><<<dim3(BATCH / 128, 512 / 128), blk, 0, stream>>>(
        R, RLD, Wpad, RLD, top_b0, hA, 512, BATCH, 512, RLD);
    // L1: [B,512] -> [B,256]
    gemm_bias_act<128, 128, 16, 8, 8, true, true><<<dim3(BATCH / 128, 256 / 128), blk, 0, stream>>>(
        hA, 512, top_w1, 512, top_b1, hB, 256, BATCH, 256, 512);
    // L2: [B,256] -> [B,1] + sigmoid
    top_final_kernel<<<dim3(BATCH / 4), blk, 0, stream>>>(hB, top_w2, top_b2, out);
}

// Round 4
// 966.954 us; speedup vs baseline: 1.0907x; 1.0907x over previous
//
#include <hip/hip_runtime.h>
#include <math.h>

// ---------------------------------------------------------------------------
// DLRM forward, split-bf16 MFMA edition.
// All big GEMMs: C = relu(A@W^T + b) with A,W decomposed to bf16 (hi,lo):
//   C ~= Ahi*Whi + Ahi*Wlo + Alo*Whi   (lo*lo term ~2^-18, negligible)
// via v_mfma_f32_16x16x32_bf16, f32 accumulation -> ~1e-4 abs error pre-act.
// ---------------------------------------------------------------------------

#define BATCH 16384
#define NTAB 26
#define NF 27
#define NROWS 100000
#define EDIM 64
#define PAIRS 351
#define RLD 416        // padded R width (415 -> 416)

typedef __attribute__((ext_vector_type(4))) float   accfrag_t;  // MFMA C/D
typedef __attribute__((ext_vector_type(8))) short   bfrag_t;    // 8 bf16 (4 VGPR)
typedef __attribute__((ext_vector_type(4))) unsigned short u16x4;

__device__ __forceinline__ unsigned short f32_to_bf16(float f) {
    unsigned int u = __float_as_uint(f);
    u += 0x7fffu + ((u >> 16) & 1u);          // RNE
    return (unsigned short)(u >> 16);
}
__device__ __forceinline__ float bf16_to_f32(unsigned short h) {
    return __uint_as_float(((unsigned int)h) << 16);
}

// async global->LDS, 16B per lane (dest must be linear in lane order, m104)
__device__ __forceinline__ void gload16(const void* g, void* l) {
    __builtin_amdgcn_global_load_lds(
        (const __attribute__((address_space(1))) unsigned int*)g,
        (__attribute__((address_space(3))) unsigned int*)l, 16, 0, 0);
}

// ---------------------------------------------------------------------------
// Split-bf16 MFMA GEMM: C[M,N] = relu(A[M,K] @ W[N,K]^T + bias)
// A,W given as hi/lo bf16 arrays, K-contiguous rows. BK=32 per tile.
// 256 threads = 4 waves (2x2); wave tile (BM/2)x(BN/2); frags FM x FN of 16x16.
// LDS layout per array: [4 k-slots][rows][8 bf16] -> frag ds_read_b128 is
// 2-way bank-aliased only (free). Staged via global_load_lds width 16.
// EPI: 0 = write hi/lo bf16; 1 = hi/lo + f32 copy; 2 = f32 only.
// ---------------------------------------------------------------------------
template<int BM, int BN, int EPI>
__global__ __launch_bounds__(256) void gemm_mfma_split(
    const unsigned short* __restrict__ Ah, const unsigned short* __restrict__ Al, int lda,
    const unsigned short* __restrict__ Wh, const unsigned short* __restrict__ Wl, int ldw,
    const float* __restrict__ bias,
    unsigned short* __restrict__ Chi, unsigned short* __restrict__ Clo, int ldc,
    float* __restrict__ Cf, int ldcf,
    int K)
{
    constexpr int FM = BM / 32;   // frags per wave in M
    constexpr int FN = BN / 32;   // frags per wave in N

    __shared__ unsigned short sAh[4 * BM * 8];
    __shared__ unsigned short sAl[4 * BM * 8];
    __shared__ unsigned short sWh[4 * BN * 8];
    __shared__ unsigned short sWl[4 * BN * 8];

    const int tid  = threadIdx.x;
    const int lane = tid & 63;
    const int wid  = tid >> 6;
    const int wr   = wid >> 1;          // wave row (0..1)
    const int wc   = wid & 1;           // wave col (0..1)
    const int lr   = lane & 15;
    const int ls   = lane >> 4;         // k-slot of this lane
    const int mblk = blockIdx.x * BM;
    const int nblk = blockIdx.y * BN;

    accfrag_t acc[FM][FN];
#pragma unroll
    for (int mi = 0; mi < FM; ++mi)
#pragma unroll
        for (int nj = 0; nj < FN; ++nj) acc[mi][nj] = (accfrag_t)0.f;

    const int ktiles = K >> 5;
    for (int kt = 0; kt < ktiles; ++kt) {
        const int k0 = kt * 32;
        // ---- stage A (hi,lo): 4*BM chunks of 16B, linear in LDS ----
#pragma unroll
        for (int i = 0; i < (4 * BM) / 256; ++i) {
            int c = tid + i * 256;
            int slot = c / BM, row = c % BM;
            size_t go = (size_t)(mblk + row) * lda + k0 + slot * 8;
            gload16(Ah + go, &sAh[c * 8]);
            gload16(Al + go, &sAl[c * 8]);
        }
        // ---- stage W (hi,lo): 4*BN chunks ----
#pragma unroll
        for (int i = 0; i < (4 * BN) / 256; ++i) {
            int c = tid + i * 256;
            int slot = c / BN, row = c % BN;
            size_t go = (size_t)(nblk + row) * ldw + k0 + slot * 8;
            gload16(Wh + go, &sWh[c * 8]);
            gload16(Wl + go, &sWl[c * 8]);
        }
        __syncthreads();   // compiler drains vmcnt before barrier

        bfrag_t ah[FM], al[FM], bh[FN], bl[FN];
#pragma unroll
        for (int mi = 0; mi < FM; ++mi) {
            int r = wr * (BM / 2) + mi * 16 + lr;
            ah[mi] = *(const bfrag_t*)&sAh[(ls * BM + r) * 8];
            al[mi] = *(const bfrag_t*)&sAl[(ls * BM + r) * 8];
        }
#pragma unroll
        for (int nj = 0; nj < FN; ++nj) {
            int cidx = wc * (BN / 2) + nj * 16 + lr;
            bh[nj] = *(const bfrag_t*)&sWh[(ls * BN + cidx) * 8];
            bl[nj] = *(const bfrag_t*)&sWl[(ls * BN + cidx) * 8];
        }
#pragma unroll
        for (int mi = 0; mi < FM; ++mi)
#pragma unroll
            for (int nj = 0; nj < FN; ++nj) {
                acc[mi][nj] = __builtin_amdgcn_mfma_f32_16x16x32_bf16(ah[mi], bh[nj], acc[mi][nj], 0, 0, 0);
                acc[mi][nj] = __builtin_amdgcn_mfma_f32_16x16x32_bf16(ah[mi], bl[nj], acc[mi][nj], 0, 0, 0);
                acc[mi][nj] = __builtin_amdgcn_mfma_f32_16x16x32_bf16(al[mi], bh[nj], acc[mi][nj], 0, 0, 0);
            }
        __syncthreads();
    }

    // ---- epilogue: C row = (lane>>4)*4 + reg, col = lane&15 (m89) ----
    float bs[FN];
#pragma unroll
    for (int nj = 0; nj < FN; ++nj)
        bs[nj] = bias[nblk + wc * (BN / 2) + nj * 16 + lr];

#pragma unroll
    for (int mi = 0; mi < FM; ++mi)
#pragma unroll
        for (int nj = 0; nj < FN; ++nj) {
            int col = nblk + wc * (BN / 2) + nj * 16 + lr;
#pragma unroll
            for (int j = 0; j < 4; ++j) {
                int row = mblk + wr * (BM / 2) + mi * 16 + ls * 4 + j;
                float v = acc[mi][nj][j] + bs[nj];
                v = v > 0.f ? v : 0.f;
                if (EPI == 0 || EPI == 1) {
                    unsigned short h = f32_to_bf16(v);
                    Chi[(size_t)row * ldc + col] = h;
                    Clo[(size_t)row * ldc + col] = f32_to_bf16(v - bf16_to_f32(h));
                }
                if (EPI == 1 || EPI == 2) {
                    Cf[(size_t)row * ldcf + col] = v;
                }
            }
        }
}

// ---------------------------------------------------------------------------
// Weight decompose: f32 [N][Kin] -> hi/lo bf16 [N][Kout], zero-padded cols.
// ---------------------------------------------------------------------------
__global__ __launch_bounds__(256) void decomp_w_kernel(
    const float* __restrict__ w, unsigned short* __restrict__ hi,
    unsigned short* __restrict__ lo, int N, int Kin, int Kout)
{
    int idx = blockIdx.x * 256 + threadIdx.x;
    if (idx >= N * Kout) return;
    int n = idx / Kout, k = idx - n * Kout;
    float v = (k < Kin) ? w[(size_t)n * Kin + k] : 0.f;
    unsigned short h = f32_to_bf16(v);
    hi[idx] = h;
    lo[idx] = f32_to_bf16(v - bf16_to_f32(h));
}

// ---------------------------------------------------------------------------
// Bottom L0 (K=13, degenerate): out hi/lo [B][512] = relu(x@w0^T + b0).
// W^T staged in LDS; 2 batch rows per block; 4 outputs per thread.
// ---------------------------------------------------------------------------
__global__ __launch_bounds__(256) void bot0_kernel(
    const float* __restrict__ x,     // [B][13]
    const float* __restrict__ w0,    // [512][13]
    const float* __restrict__ b0,    // [512]
    unsigned short* __restrict__ oh, unsigned short* __restrict__ ol)
{
    __shared__ float Wt[13][512];
    __shared__ float xs[2][13];
    __shared__ float bsh[512];
    const int tid = threadIdx.x;
    for (int i = tid; i < 13 * 512; i += 256) {
        int n = i / 13, k = i - n * 13;
        Wt[k][n] = w0[i];
    }
    bsh[tid] = b0[tid];
    bsh[tid + 256] = b0[tid + 256];
    const int brow0 = blockIdx.x * 2;
    if (tid < 26) xs[tid / 13][tid % 13] = x[(size_t)brow0 * 13 + tid];
    __syncthreads();

    const int bl = tid >> 7;              // 0..1
    const int n0 = (tid & 127) * 4;
    const int b  = brow0 + bl;
    float a0 = bsh[n0], a1 = bsh[n0 + 1], a2 = bsh[n0 + 2], a3 = bsh[n0 + 3];
#pragma unroll
    for (int k = 0; k < 13; ++k) {
        float xv = xs[bl][k];
        float4 wv = *(const float4*)&Wt[k][n0];
        a0 += xv * wv.x; a1 += xv * wv.y; a2 += xv * wv.z; a3 += xv * wv.w;
    }
    a0 = fmaxf(a0, 0.f); a1 = fmaxf(a1, 0.f); a2 = fmaxf(a2, 0.f); a3 = fmaxf(a3, 0.f);
    u16x4 h, l;
    h.x = f32_to_bf16(a0); l.x = f32_to_bf16(a0 - bf16_to_f32(h.x));
    h.y = f32_to_bf16(a1); l.y = f32_to_bf16(a1 - bf16_to_f32(h.y));
    h.z = f32_to_bf16(a2); l.z = f32_to_bf16(a2 - bf16_to_f32(h.z));
    h.w = f32_to_bf16(a3); l.w = f32_to_bf16(a3 - bf16_to_f32(h.w));
    *(u16x4*)&oh[(size_t)b * 512 + n0] = h;
    *(u16x4*)&ol[(size_t)b * 512 + n0] = l;
}

// ---------------------------------------------------------------------------
// Fused embedding gather + pairwise interaction.
// Reads x (f32) from xf, writes Z hi/lo into R[.,64..414], zeroes col 415.
// ---------------------------------------------------------------------------
__global__ __launch_bounds__(256) void interact_kernel(
    const float* __restrict__ emb,   // [26][100000][64]
    const int*   __restrict__ lsi,   // [26][B]
    const float* __restrict__ xf,    // [B][64]
    unsigned short* __restrict__ Rhi, unsigned short* __restrict__ Rlo) // [B][416]
{
    __shared__ float Tl[4][NF][68];
    const int wave = threadIdx.x >> 6;
    const int lane = threadIdx.x & 63;
    const int b = blockIdx.x * 4 + wave;

    Tl[wave][0][lane] = xf[(size_t)b * EDIM + lane];
#pragma unroll 2
    for (int t = 0; t < NTAB; ++t) {
        int row = lsi[t * BATCH + b];
        Tl[wave][t + 1][lane] = emb[((size_t)t * NROWS + row) * EDIM + lane];
    }
    __syncthreads();

    for (int p = lane; p < PAIRS; p += 64) {
        int i = (int)((1.0f + sqrtf(1.0f + 8.0f * (float)p)) * 0.5f);
        while (i * (i - 1) / 2 > p) --i;
        while ((i + 1) * i / 2 <= p) ++i;
        int j = p - i * (i - 1) / 2;

        const float4* ri = (const float4*)&Tl[wave][i][0];
        const float4* rj = (const float4*)&Tl[wave][j][0];
        float s = 0.f;
#pragma unroll
        for (int d = 0; d < EDIM / 4; ++d) {
            float4 a = ri[d], c = rj[d];
            s += a.x * c.x + a.y * c.y + a.z * c.z + a.w * c.w;
        }
        size_t o = (size_t)b * RLD + EDIM + p;
        unsigned short h = f32_to_bf16(s);
        Rhi[o] = h;
        Rlo[o] = f32_to_bf16(s - bf16_to_f32(h));
    }
    if (lane == 0) {               // col 415: zero both (poison-safe, 0*0=0)
        size_t o = (size_t)b * RLD + 415;
        Rhi[o] = 0;
        Rlo[o] = 0;
    }
}

// ---------------------------------------------------------------------------
// Final layer: out[b] = sigmoid(dot(h[b], w) + bias). One wave per row.
// ---------------------------------------------------------------------------
__global__ __launch_bounds__(256) void top_final_kernel(
    const float* __restrict__ h,     // [B][256] f32
    const float* __restrict__ w,     // [256]
    const float* __restrict__ bias,  // [1]
    float* __restrict__ out)
{
    const int wave = threadIdx.x >> 6;
    const int lane = threadIdx.x & 63;
    const int b = blockIdx.x * 4 + wave;

    const float4* hv = (const float4*)&h[(size_t)b * 256];
    const float4* wv = (const float4*)w;
    float4 a = hv[lane];
    float4 c = wv[lane];
    float s = a.x * c.x + a.y * c.y + a.z * c.z + a.w * c.w;
#pragma unroll
    for (int off = 32; off; off >>= 1) s += __shfl_down(s, off);
    if (lane == 0) {
        float z = s + bias[0];
        out[b] = 1.f / (1.f + expf(-z));
    }
}

// ---------------------------------------------------------------------------
extern "C" void kernel_launch(void* const* d_in, const int* in_sizes, int n_in,
                              void* d_out, int out_size, void* d_ws, size_t ws_size,
                              hipStream_t stream)
{
    const float* dense_x = (const float*)d_in[0];
    const int*   lS_i    = (const int*)  d_in[1];
    const float* emb_W   = (const float*)d_in[2];
    const float* bot_w0  = (const float*)d_in[3];
    const float* bot_b0  = (const float*)d_in[4];
    const float* bot_w1  = (const float*)d_in[5];
    const float* bot_b1  = (const float*)d_in[6];
    const float* bot_w2  = (const float*)d_in[7];
    const float* bot_b2  = (const float*)d_in[8];
    const float* top_w0  = (const float*)d_in[9];
    const float* top_b0  = (const float*)d_in[10];
    const float* top_w1  = (const float*)d_in[11];
    const float* top_b1  = (const float*)d_in[12];
    const float* top_w2  = (const float*)d_in[13];
    const float* top_b2  = (const float*)d_in[14];
    float* out = (float*)d_out;

    // ---- workspace layout ----
    unsigned short* p = (unsigned short*)d_ws;
    unsigned short* hAhi = p; p += (size_t)BATCH * 512;
    unsigned short* hAlo = p; p += (size_t)BATCH * 512;
    unsigned short* hBhi = p; p += (size_t)BATCH * 256;
    unsigned short* hBlo = p; p += (size_t)BATCH * 256;
    unsigned short* Rhi  = p; p += (size_t)BATCH * RLD;
    unsigned short* Rlo  = p; p += (size_t)BATCH * RLD;
    float* xf  = (float*)p;          // 16B-aligned (prefix is 77,594,624 B)
    float* hBf = xf + (size_t)BATCH * EDIM;
    unsigned short* q = (unsigned short*)(hBf + (size_t)BATCH * 256);
    unsigned short* w1h = q; q += 256 * 512;
    unsigned short* w1l = q; q += 256 * 512;
    unsigned short* w2h = q; q += 64 * 256;
    unsigned short* w2l = q; q += 64 * 256;
    unsigned short* t0h = q; q += 512 * RLD;
    unsigned short* t0l = q; q += 512 * RLD;
    unsigned short* t1h = q; q += 256 * 512;
    unsigned short* t1l = q; q += 256 * 512;

    dim3 blk(256);

    // ---- decompose weights (tiny) ----
    decomp_w_kernel<<<dim3((256 * 512 + 255) / 256), blk, 0, stream>>>(bot_w1, w1h, w1l, 256, 512, 512);
    decomp_w_kernel<<<dim3((64 * 256 + 255) / 256), blk, 0, stream>>>(bot_w2, w2h, w2l, 64, 256, 256);
    decomp_w_kernel<<<dim3((512 * RLD + 255) / 256), blk, 0, stream>>>(top_w0, t0h, t0l, 512, 415, RLD);
    decomp_w_kernel<<<dim3((256 * 512 + 255) / 256), blk, 0, stream>>>(top_w1, t1h, t1l, 256, 512, 512);

    // ---- bottom MLP ----
    bot0_kernel<<<dim3(BATCH / 2), blk, 0, stream>>>(dense_x, bot_w0, bot_b0, hAhi, hAlo);
    // L1: [B,512] -> [B,256] hi/lo
    gemm_mfma_split<64, 128, 0><<<dim3(BATCH / 64, 256 / 128), blk, 0, stream>>>(
        hAhi, hAlo, 512, w1h, w1l, 512, bot_b1, hBhi, hBlo, 256, nullptr, 0, 512);
    // L2: [B,256] -> [B,64]: hi/lo into R[:,0:64] (ldc=416) + f32 into xf
    gemm_mfma_split<64, 64, 1><<<dim3(BATCH / 64, 1), blk, 0, stream>>>(
        hBhi, hBlo, 256, w2h, w2l, 256, bot_b2, Rhi, Rlo, RLD, xf, EDIM, 256);

    // ---- gather + interaction -> R[:,64:415] hi/lo, col 415 zeroed ----
    interact_kernel<<<dim3(BATCH / 4), blk, 0, stream>>>(emb_W, lS_i, xf, Rhi, Rlo);

    // ---- top MLP ----
    // L0: [B,416] -> [B,512] hi/lo
    gemm_mfma_split<64, 128, 0><<<dim3(BATCH / 64, 512 / 128), blk, 0, stream>>>(
        Rhi, Rlo, RLD, t0h, t0l, RLD, top_b0, hAhi, hAlo, 512, nullptr, 0, RLD);
    // L1: [B,512] -> [B,256] f32
    gemm_mfma_split<64, 128, 2><<<dim3(BATCH / 64, 256 / 128), blk, 0, stream>>>(
        hAhi, hAlo, 512, t1h, t1l, 512, top_b1, nullptr, nullptr, 0, hBf, 256, 512);
    // L2: [B,256] -> [B,1] + sigmoid
    top_final_kernel<<<dim3(BATCH / 4), blk, 0, stream>>>(hBf, top_w2, top_b2, out);
}

// Round 9
// 942.535 us; speedup vs baseline: 1.1190x; 1.0259x over previous
//
#include <hip/hip_runtime.h>
#include <math.h>

// ---------------------------------------------------------------------------
// DLRM forward, split-bf16 MFMA edition, round 5 (resubmit; infra fails x4).
// C = relu(A@W^T + b) with A,W decomposed to bf16 (hi,lo):
//   C ~= Ahi*Whi + Ahi*Wlo + Alo*Whi  (lo*lo ~2^-18, negligible)
// via v_mfma_f32_16x16x32_bf16, f32 accumulation.
// 7 launches: decomp_all, botL0(gemm), botL1, botL2(+f32 x), interact,
//             topL0, topL1(+fused final dot+sigmoid).
// ---------------------------------------------------------------------------

#define BATCH 16384
#define NTAB 26
#define NF 27
#define NROWS 100000
#define EDIM 64
#define PAIRS 351
#define RLD 416        // padded R width (415 -> 416)
#define XK 32          // padded K for bottom L0 (13 -> 32)

typedef __attribute__((ext_vector_type(4))) float accfrag_t;
typedef __attribute__((ext_vector_type(8))) short bfrag_t;

__device__ __forceinline__ unsigned short f32_to_bf16(float f) {
    unsigned int u = __float_as_uint(f);
    u += 0x7fffu + ((u >> 16) & 1u);          // RNE
    return (unsigned short)(u >> 16);
}
__device__ __forceinline__ float bf16_to_f32(unsigned short h) {
    return __uint_as_float(((unsigned int)h) << 16);
}

// async global->LDS, 16B per lane (LDS dest linear in lane order, m104)
__device__ __forceinline__ void gload16(const void* g, void* l) {
    __builtin_amdgcn_global_load_lds(
        (const __attribute__((address_space(1))) unsigned int*)g,
        (__attribute__((address_space(3))) unsigned int*)l, 16, 0, 0);
}

// ---------------------------------------------------------------------------
// Split-bf16 MFMA GEMM: C[M,N] = relu(A[M,K] @ W[N,K]^T + bias)
// BK=32; 256 threads = 4 waves (2x2); wave tile (BM/2)x(BN/2).
// LDS per array: [4 k-slots][rows][8 bf16]; staged via global_load_lds w=16.
// EPI: 0 = write hi/lo bf16; 1 = hi/lo + f32 copy;
//      3 = fused final layer: out[row] = sigmoid(dot(relu(C_row), wfin) + bfin)
//          (requires BN == N, i.e. gridDim.y == 1)
// ---------------------------------------------------------------------------
template<int BM, int BN, int EPI>
__global__ __launch_bounds__(256) void gemm_mfma_split(
    const unsigned short* __restrict__ Ah, const unsigned short* __restrict__ Al, int lda,
    const unsigned short* __restrict__ Wh, const unsigned short* __restrict__ Wl, int ldw,
    const float* __restrict__ bias,
    unsigned short* __restrict__ Chi, unsigned short* __restrict__ Clo, int ldc,
    float* __restrict__ Cf, int ldcf,
    const float* __restrict__ wfin, const float* __restrict__ bfin,
    float* __restrict__ outp,
    int K)
{
    constexpr int FM = BM / 32;
    constexpr int FN = BN / 32;

    __shared__ unsigned short sAh[4 * BM * 8];
    __shared__ unsigned short sAl[4 * BM * 8];
    __shared__ unsigned short sWh[4 * BN * 8];
    __shared__ unsigned short sWl[4 * BN * 8];

    const int tid  = threadIdx.x;
    const int lane = tid & 63;
    const int wid  = tid >> 6;
    const int wr   = wid >> 1;
    const int wc   = wid & 1;
    const int lr   = lane & 15;
    const int ls   = lane >> 4;
    const int mblk = blockIdx.x * BM;
    const int nblk = blockIdx.y * BN;

    accfrag_t acc[FM][FN];
#pragma unroll
    for (int mi = 0; mi < FM; ++mi)
#pragma unroll
        for (int nj = 0; nj < FN; ++nj) acc[mi][nj] = (accfrag_t)0.f;

    const int ktiles = K >> 5;
    for (int kt = 0; kt < ktiles; ++kt) {
        const int k0 = kt * 32;
#pragma unroll
        for (int i = 0; i < (4 * BM) / 256; ++i) {
            int c = tid + i * 256;
            int slot = c / BM, row = c % BM;
            size_t go = (size_t)(mblk + row) * lda + k0 + slot * 8;
            gload16(Ah + go, &sAh[c * 8]);
            gload16(Al + go, &sAl[c * 8]);
        }
#pragma unroll
        for (int i = 0; i < (4 * BN) / 256; ++i) {
            int c = tid + i * 256;
            int slot = c / BN, row = c % BN;
            size_t go = (size_t)(nblk + row) * ldw + k0 + slot * 8;
            gload16(Wh + go, &sWh[c * 8]);
            gload16(Wl + go, &sWl[c * 8]);
        }
        __syncthreads();

        bfrag_t ah[FM], al[FM], bh[FN], bl[FN];
#pragma unroll
        for (int mi = 0; mi < FM; ++mi) {
            int r = wr * (BM / 2) + mi * 16 + lr;
            ah[mi] = *(const bfrag_t*)&sAh[(ls * BM + r) * 8];
            al[mi] = *(const bfrag_t*)&sAl[(ls * BM + r) * 8];
        }
#pragma unroll
        for (int nj = 0; nj < FN; ++nj) {
            int cidx = wc * (BN / 2) + nj * 16 + lr;
            bh[nj] = *(const bfrag_t*)&sWh[(ls * BN + cidx) * 8];
            bl[nj] = *(const bfrag_t*)&sWl[(ls * BN + cidx) * 8];
        }
#pragma unroll
        for (int mi = 0; mi < FM; ++mi)
#pragma unroll
            for (int nj = 0; nj < FN; ++nj) {
                acc[mi][nj] = __builtin_amdgcn_mfma_f32_16x16x32_bf16(ah[mi], bh[nj], acc[mi][nj], 0, 0, 0);
                acc[mi][nj] = __builtin_amdgcn_mfma_f32_16x16x32_bf16(ah[mi], bl[nj], acc[mi][nj], 0, 0, 0);
                acc[mi][nj] = __builtin_amdgcn_mfma_f32_16x16x32_bf16(al[mi], bh[nj], acc[mi][nj], 0, 0, 0);
            }
        __syncthreads();
    }

    // C/D layout (m89): col = lane&15, row = (lane>>4)*4 + reg
    float bs[FN];
#pragma unroll
    for (int nj = 0; nj < FN; ++nj)
        bs[nj] = bias[nblk + wc * (BN / 2) + nj * 16 + lr];

    if constexpr (EPI == 3) {
        // fused final: per-row dot(relu(C_row), wfin) -> sigmoid -> outp
        __shared__ float red[BM][2];
        float wv[FN];
#pragma unroll
        for (int nj = 0; nj < FN; ++nj)
            wv[nj] = wfin[wc * (BN / 2) + nj * 16 + lr];
#pragma unroll
        for (int mi = 0; mi < FM; ++mi)
#pragma unroll
            for (int j = 0; j < 4; ++j) {
                float part = 0.f;
#pragma unroll
                for (int nj = 0; nj < FN; ++nj) {
                    float v = acc[mi][nj][j] + bs[nj];
                    v = v > 0.f ? v : 0.f;
                    part += v * wv[nj];
                }
                // reduce across the 16 lanes (lr) holding this row's columns
#pragma unroll
                for (int off = 1; off < 16; off <<= 1)
                    part += __shfl_xor(part, off);
                if (lr == 0)
                    red[wr * (BM / 2) + mi * 16 + ls * 4 + j][wc] = part;
            }
        __syncthreads();
        if (tid < BM) {
            float s = red[tid][0] + red[tid][1] + bfin[0];
            outp[mblk + tid] = 1.f / (1.f + expf(-s));
        }
    } else {
#pragma unroll
        for (int mi = 0; mi < FM; ++mi)
#pragma unroll
            for (int nj = 0; nj < FN; ++nj) {
                int col = nblk + wc * (BN / 2) + nj * 16 + lr;
#pragma unroll
                for (int j = 0; j < 4; ++j) {
                    int row = mblk + wr * (BM / 2) + mi * 16 + ls * 4 + j;
                    float v = acc[mi][nj][j] + bs[nj];
                    v = v > 0.f ? v : 0.f;
                    unsigned short h = f32_to_bf16(v);
                    Chi[(size_t)row * ldc + col] = h;
                    Clo[(size_t)row * ldc + col] = f32_to_bf16(v - bf16_to_f32(h));
                    if (EPI == 1) Cf[(size_t)row * ldcf + col] = v;
                }
            }
    }
}

// ---------------------------------------------------------------------------
// One-shot decomposition of x (padded to K=32) and all weights into hi/lo
// bf16 (with column zero-padding where K is padded). Segmented by blockIdx.
// ---------------------------------------------------------------------------
#define XB_   2048   // BATCH*32/256
#define W0B_  64     // 512*32/256
#define W1B_  512    // 256*512/256
#define W2B_  64     // 64*256/256
#define T0B_  832    // 512*416/256
#define T1B_  512    // 256*512/256

__global__ __launch_bounds__(256) void decomp_all(
    const float* __restrict__ x,   // [B][13]
    const float* __restrict__ w0,  // [512][13]
    const float* __restrict__ w1,  // [256][512]
    const float* __restrict__ w2,  // [64][256]
    const float* __restrict__ t0,  // [512][415]
    const float* __restrict__ t1,  // [256][512]
    unsigned short* __restrict__ xh,  unsigned short* __restrict__ xl,
    unsigned short* __restrict__ w0h, unsigned short* __restrict__ w0l,
    unsigned short* __restrict__ w1h, unsigned short* __restrict__ w1l,
    unsigned short* __restrict__ w2h, unsigned short* __restrict__ w2l,
    unsigned short* __restrict__ t0h, unsigned short* __restrict__ t0l,
    unsigned short* __restrict__ t1h, unsigned short* __restrict__ t1l)
{
    const int blk = blockIdx.x;
    const int t = threadIdx.x;
    float v;
    unsigned short* hi;
    unsigned short* lo;
    int idx;
    if (blk < XB_) {
        idx = blk * 256 + t;
        int b = idx >> 5, k = idx & 31;
        v = (k < 13) ? x[b * 13 + k] : 0.f;
        hi = xh; lo = xl;
    } else if (blk < XB_ + W0B_) {
        idx = (blk - XB_) * 256 + t;
        int n = idx >> 5, k = idx & 31;
        v = (k < 13) ? w0[n * 13 + k] : 0.f;
        hi = w0h; lo = w0l;
    } else if (blk < XB_ + W0B_ + W1B_) {
        idx = (blk - XB_ - W0B_) * 256 + t;
        v = w1[idx];
        hi = w1h; lo = w1l;
    } else if (blk < XB_ + W0B_ + W1B_ + W2B_) {
        idx = (blk - XB_ - W0B_ - W1B_) * 256 + t;
        v = w2[idx];
        hi = w2h; lo = w2l;
    } else if (blk < XB_ + W0B_ + W1B_ + W2B_ + T0B_) {
        idx = (blk - XB_ - W0B_ - W1B_ - W2B_) * 256 + t;
        int n = idx / RLD, k = idx - n * RLD;
        v = (k < 415) ? t0[n * 415 + k] : 0.f;
        hi = t0h; lo = t0l;
    } else {
        idx = (blk - XB_ - W0B_ - W1B_ - W2B_ - T0B_) * 256 + t;
        v = t1[idx];
        hi = t1h; lo = t1l;
    }
    unsigned short h = f32_to_bf16(v);
    hi[idx] = h;
    lo[idx] = f32_to_bf16(v - bf16_to_f32(h));
}

// ---------------------------------------------------------------------------
// Fused embedding gather + pairwise interaction.
// Reads x (f32) from xf, writes Z hi/lo into R[.,64..414], zeroes col 415.
// ---------------------------------------------------------------------------
__global__ __launch_bounds__(256) void interact_kernel(
    const float* __restrict__ emb,   // [26][100000][64]
    const int*   __restrict__ lsi,   // [26][B]
    const float* __restrict__ xf,    // [B][64]
    unsigned short* __restrict__ Rhi, unsigned short* __restrict__ Rlo) // [B][416]
{
    __shared__ float Tl[4][NF][68];
    const int wave = threadIdx.x >> 6;
    const int lane = threadIdx.x & 63;
    const int b = blockIdx.x * 4 + wave;

    Tl[wave][0][lane] = xf[(size_t)b * EDIM + lane];
#pragma unroll 2
    for (int t = 0; t < NTAB; ++t) {
        int row = lsi[t * BATCH + b];
        Tl[wave][t + 1][lane] = emb[((size_t)t * NROWS + row) * EDIM + lane];
    }
    __syncthreads();

    for (int p = lane; p < PAIRS; p += 64) {
        int i = (int)((1.0f + sqrtf(1.0f + 8.0f * (float)p)) * 0.5f);
        while (i * (i - 1) / 2 > p) --i;
        while ((i + 1) * i / 2 <= p) ++i;
        int j = p - i * (i - 1) / 2;

        const float4* ri = (const float4*)&Tl[wave][i][0];
        const float4* rj = (const float4*)&Tl[wave][j][0];
        float s = 0.f;
#pragma unroll
        for (int d = 0; d < EDIM / 4; ++d) {
            float4 a = ri[d], c = rj[d];
            s += a.x * c.x + a.y * c.y + a.z * c.z + a.w * c.w;
        }
        size_t o = (size_t)b * RLD + EDIM + p;
        unsigned short h = f32_to_bf16(s);
        Rhi[o] = h;
        Rlo[o] = f32_to_bf16(s - bf16_to_f32(h));
    }
    if (lane == 0) {
        size_t o = (size_t)b * RLD + 415;
        Rhi[o] = 0;
        Rlo[o] = 0;
    }
}

// ---------------------------------------------------------------------------
extern "C" void kernel_launch(void* const* d_in, const int* in_sizes, int n_in,
                              void* d_out, int out_size, void* d_ws, size_t ws_size,
                              hipStream_t stream)
{
    const float* dense_x = (const float*)d_in[0];
    const int*   lS_i    = (const int*)  d_in[1];
    const float* emb_W   = (const float*)d_in[2];
    const float* bot_w0  = (const float*)d_in[3];
    const float* bot_b0  = (const float*)d_in[4];
    const float* bot_w1  = (const float*)d_in[5];
    const float* bot_b1  = (const float*)d_in[6];
    const float* bot_w2  = (const float*)d_in[7];
    const float* bot_b2  = (const float*)d_in[8];
    const float* top_w0  = (const float*)d_in[9];
    const float* top_b0  = (const float*)d_in[10];
    const float* top_w1  = (const float*)d_in[11];
    const float* top_b1  = (const float*)d_in[12];
    const float* top_w2  = (const float*)d_in[13];
    const float* top_b2  = (const float*)d_in[14];
    float* out = (float*)d_out;

    // ---- workspace layout (f32 first, then bf16 arrays; all 16B aligned) ----
    float* xf = (float*)d_ws;                                  // [B][64]
    unsigned short* p = (unsigned short*)(xf + (size_t)BATCH * EDIM);
    unsigned short* hAhi = p; p += (size_t)BATCH * 512;
    unsigned short* hAlo = p; p += (size_t)BATCH * 512;
    unsigned short* hBhi = p; p += (size_t)BATCH * 256;
    unsigned short* hBlo = p; p += (size_t)BATCH * 256;
    unsigned short* Rhi  = p; p += (size_t)BATCH * RLD;
    unsigned short* Rlo  = p; p += (size_t)BATCH * RLD;
    unsigned short* xh   = p; p += (size_t)BATCH * XK;
    unsigned short* xl   = p; p += (size_t)BATCH * XK;
    unsigned short* w0h  = p; p += 512 * XK;
    unsigned short* w0l  = p; p += 512 * XK;
    unsigned short* w1h  = p; p += 256 * 512;
    unsigned short* w1l  = p; p += 256 * 512;
    unsigned short* w2h  = p; p += 64 * 256;
    unsigned short* w2l  = p; p += 64 * 256;
    unsigned short* t0h  = p; p += 512 * RLD;
    unsigned short* t0l  = p; p += 512 * RLD;
    unsigned short* t1h  = p; p += 256 * 512;
    unsigned short* t1l  = p; p += 256 * 512;

    dim3 blk(256);

    // 1) decompose x + all weights (one kernel)
    decomp_all<<<dim3(XB_ + W0B_ + W1B_ + W2B_ + T0B_ + T1B_), blk, 0, stream>>>(
        dense_x, bot_w0, bot_w1, bot_w2, top_w0, top_w1,
        xh, xl, w0h, w0l, w1h, w1l, w2h, w2l, t0h, t0l, t1h, t1l);

    // 2) bottom L0: [B,32pad] -> [B,512] hi/lo
    gemm_mfma_split<64, 128, 0><<<dim3(BATCH / 64, 512 / 128), blk, 0, stream>>>(
        xh, xl, XK, w0h, w0l, XK, bot_b0, hAhi, hAlo, 512,
        nullptr, 0, nullptr, nullptr, nullptr, XK);

    // 3) bottom L1: [B,512] -> [B,256] hi/lo
    gemm_mfma_split<64, 128, 0><<<dim3(BATCH / 64, 256 / 128), blk, 0, stream>>>(
        hAhi, hAlo, 512, w1h, w1l, 512, bot_b1, hBhi, hBlo, 256,
        nullptr, 0, nullptr, nullptr, nullptr, 512);

    // 4) bottom L2: [B,256] -> [B,64]: hi/lo into R[:,0:64] + f32 into xf
    gemm_mfma_split<64, 64, 1><<<dim3(BATCH / 64, 1), blk, 0, stream>>>(
        hBhi, hBlo, 256, w2h, w2l, 256, bot_b2, Rhi, Rlo, RLD,
        xf, EDIM, nullptr, nullptr, nullptr, 256);

    // 5) gather + interaction -> R[:,64:415] hi/lo, col 415 zeroed
    interact_kernel<<<dim3(BATCH / 4), blk, 0, stream>>>(emb_W, lS_i, xf, Rhi, Rlo);

    // 6) top L0: [B,416] -> [B,512] hi/lo
    gemm_mfma_split<64, 128, 0><<<dim3(BATCH / 64, 512 / 128), blk, 0, stream>>>(
        Rhi, Rlo, RLD, t0h, t0l, RLD, top_b0, hAhi, hAlo, 512,
        nullptr, 0, nullptr, nullptr, nullptr, RLD);

    // 7) top L1 + fused final: [B,512] -> [B,256] -> dot w2 + sigmoid -> out
    gemm_mfma_split<64, 256, 3><<<dim3(BATCH / 64, 1), blk, 0, stream>>>(
        hAhi, hAlo, 512, t1h, t1l, 512, top_b1, nullptr, nullptr, 0,
        nullptr, 0, top_w2, top_b2, out, 512);
}